// Round 2
// baseline (289.281 us; speedup 1.0000x reference)
//
#include <hip/hip_runtime.h>

// ChebyKANLayer: y[t,o] = bias[o] + sum_k A[t,k]*B[k,o], K=8192, k=i*8+(d-1), d=1..8.
// R8: 8-phase-style pipelined GEMM (T3+T4+T5+T1): 256x128 block, 512 thr, 8 waves,
// A in 4-deep LDS ring via global_load_lds (staged t+2), B global->reg (t+2),
// counted vmcnt(12) once per K-step (never 0 in loop), setprio around MFMA clusters.
// A/B fragment-packed global images unchanged from verified R7 kernel.

typedef __bf16 bf16;
typedef __bf16 bf16x8 __attribute__((ext_vector_type(8)));
typedef float f32x2 __attribute__((ext_vector_type(2)));
typedef float f32x4 __attribute__((ext_vector_type(4)));
typedef float f32x16 __attribute__((ext_vector_type(16)));

#define MFMA __builtin_amdgcn_mfma_f32_32x32x16_bf16

__device__ __forceinline__ void g2lds16(const void* g, void* l) {
  __builtin_amdgcn_global_load_lds(
      (const __attribute__((address_space(1))) unsigned int*)g,
      (__attribute__((address_space(3))) unsigned int*)l, 16, 0, 0);
}

__device__ __forceinline__ float fast_tanh(float a) {
  float e = __expf(a + a);
  return 1.f - 2.f * __builtin_amdgcn_rcpf(e + 1.f);   // saturating, NaN-free
}

// ============================ PREP ============================
// A global layout: [mb 0..63][kt 0..127][tile image 8192 bf16], tile image elem:
//   (((ks*4 + m32)*2 + h)*32 + ml)*8 + j   with i = kt*8 + 2*ks + h, d = j+1,
//   row r in 128-slice: m32 = r>>5, ml = r&31.
// B global layout: [nb 0..7][kt 0..127][8192], same k mapping, cols n32=(o&127)>>5, ml=o&31.
// bias_p[p][o] = sum_{i in 32-block p} C[i][o][0].
__global__ __launch_bounds__(256)
void cheby_prep2(const float* __restrict__ x, const float* __restrict__ C,
                 bf16* __restrict__ A, bf16* __restrict__ B,
                 float* __restrict__ bias_p) {
  const int bid = blockIdx.x, tid = threadIdx.x;
  if (bid < 1024) {                                  // ---- A-gen: 128 rows x 64 i per block
    const int mb = bid >> 4, ig = bid & 15;
    const int rl = tid & 127, ih = tid >> 7;
    const int m32 = rl >> 5, ml = rl & 31;
    const int i_base = ig * 64 + ih * 32;
    const float* xp = x + (size_t)(mb * 128 + rl) * 1024 + i_base;
    bf16* aout = A + (size_t)mb * 128 * 8192;
    #pragma unroll 2
    for (int q = 0; q < 8; ++q) {
      f32x4 xv = *(const f32x4*)(xp + q * 4);
      #pragma unroll
      for (int j = 0; j < 4; ++j) {
        const int ia = i_base + q * 4 + j;
        const int kt = ia >> 3, cc = ia & 7;
        float z = fast_tanh(xv[j]);
        float z2 = z + z, pv = 1.f, cv = z;
        bf16x8 v;
        #pragma unroll
        for (int d = 0; d < 8; ++d) {
          v[d] = (bf16)cv;
          float nx = z2 * cv - pv; pv = cv; cv = nx;
        }
        const int widx = (((cc >> 1) * 4 + m32) * 2 + (cc & 1)) * 32 + ml;
        *(bf16x8*)(aout + (size_t)kt * 8192 + widx * 8) = v;
      }
    }
    return;
  }
  // ---- B repack + bias partials: 32 i x 32 o per block (1024 blocks)
  const int b2 = bid - 1024;
  __shared__ float tile[32][292];
  const int i0 = (b2 >> 5) * 32, o0 = (b2 & 31) * 32;
  {
    const int r = tid >> 3, seg = tid & 7;
    const float* src = C + (size_t)(i0 + r) * 9216 + (size_t)o0 * 9 + seg * 36;
    float* dst = &tile[r][seg * 36];
    #pragma unroll
    for (int v = 0; v < 9; ++v) *(f32x4*)(dst + v * 4) = *(const f32x4*)(src + v * 4);
  }
  __syncthreads();
  #pragma unroll
  for (int j = 0; j < 4; ++j) {
    int e = tid + 256 * j;
    int il = e >> 5, ol = e & 31;
    int i = i0 + il, o = o0 + ol;
    bf16x8 v;
    #pragma unroll
    for (int d = 0; d < 8; ++d) v[d] = (bf16)tile[il][ol * 9 + 1 + d];
    const int cc = i & 7;
    size_t tnum = (size_t)(o >> 7) * 128 + (i >> 3);
    const int widx = (((cc >> 1) * 4 + ((o & 127) >> 5)) * 2 + (cc & 1)) * 32 + (o & 31);
    *(bf16x8*)(B + tnum * 8192 + widx * 8) = v;
  }
  if (tid < 32) {
    float s = 0.f;
    #pragma unroll
    for (int i = 0; i < 32; ++i) s += tile[i][tid * 9];
    bias_p[(size_t)(b2 >> 5) * 1024 + o0 + tid] = s;
  }
}

// ============================ GEMM (8-phase pipelined) ============================
__global__ __launch_bounds__(512, 2)
void cheby_gemm3(const bf16* __restrict__ A, const bf16* __restrict__ B,
                 const float* __restrict__ bias_p, float* __restrict__ out) {
  __shared__ bf16 As[4][16384];                      // 4 x 32KB ring
  const int tid = threadIdx.x;
  const int lane = tid & 63, w = tid >> 6;
  const int wm = w >> 1, wn = w & 1;                 // 4M x 2N waves, wave tile 64x64
  const int bid = blockIdx.x;
  const int wgid = (bid & 7) * 32 + (bid >> 3);      // XCD-chunked, bijective (256 = 8*32)
  const int mb2 = wgid >> 3, nb = wgid & 7;          // rows [mb2*256, +256), cols [nb*128, +128)

  const int ml = lane & 31, h = lane >> 5;
  const int aoff = h * 256 + ml * 8;                 // lane part of A-frag elem offset
  // per-(wave,msub) constant part: slice*8192 + m32*512
  const int sBase0 = ((wm * 64) >> 7) * 8192 + ((wm * 2) & 3) * 512;
  const int sBase1 = (((wm * 64 + 32) >> 7)) * 8192 + ((wm * 2 + 1) & 3) * 512;

  const bf16* aG = A + (size_t)(mb2 * 2) * 128 * 8192 + tid * 8;
  const bf16* bG = B + (size_t)nb * 128 * 8192 + wn * 1024 + lane * 8;

  f32x16 acc[2][2];
  #pragma unroll
  for (int a = 0; a < 2; ++a)
    #pragma unroll
    for (int b = 0; b < 2; ++b)
      #pragma unroll
      for (int r = 0; r < 16; ++r) acc[a][b][r] = 0.f;

  bf16x8 bA[4][2], bB[4][2];

  // stage chunk-pair cp (0: c0,c1 ; 1: c2,c3) of A-tile t into ring buffer buf
  auto issueA2 = [&](int t, int buf, int cp) {
    #pragma unroll
    for (int cc2 = 0; cc2 < 2; ++cc2) {
      const int c = cp * 2 + cc2;
      g2lds16(aG + (size_t)(c >> 1) * 1048576 + (size_t)t * 8192 + (c & 1) * 4096,
              &As[buf][c * 4096 + tid * 8]);
    }
  };
  auto loadB = [&](bf16x8 (&dst)[4][2], int t) {
    const bf16* g = bG + (size_t)t * 8192;
    #pragma unroll
    for (int ks = 0; ks < 4; ++ks)
      #pragma unroll
      for (int nt = 0; nt < 2; ++nt)
        dst[ks][nt] = *(const bf16x8*)(g + (ks * 256 + nt * 64) * 8);
  };

  // prologue: A(0)->buf0, A(1)->buf1, B(0), B(1); drain A(0) (keep 20), barrier
  issueA2(0, 0, 0); issueA2(0, 0, 1);
  issueA2(1, 1, 0); issueA2(1, 1, 1);
  loadB(bA, 0); loadB(bB, 1);
  asm volatile("s_waitcnt vmcnt(20)" ::: "memory");
  __builtin_amdgcn_s_barrier();

  auto step = [&](int t, int buf, bf16x8 (&bfr)[4][2]) {
    const bf16* asb = &As[buf][0];
    // ---- phase 0: ks 0,1 ----
    {
      bf16x8 a00 = *(const bf16x8*)(asb + sBase0 + 0 * 2048 + aoff);
      bf16x8 a10 = *(const bf16x8*)(asb + sBase1 + 0 * 2048 + aoff);
      bf16x8 a01 = *(const bf16x8*)(asb + sBase0 + 1 * 2048 + aoff);
      bf16x8 a11 = *(const bf16x8*)(asb + sBase1 + 1 * 2048 + aoff);
      if (t < 126) issueA2(t + 2, (t + 2) & 3, 0);   // A(t+2) chunks 0,1
      __builtin_amdgcn_s_barrier();
      __builtin_amdgcn_s_setprio(1);
      acc[0][0] = MFMA(a00, bfr[0][0], acc[0][0], 0, 0, 0);
      acc[0][1] = MFMA(a00, bfr[0][1], acc[0][1], 0, 0, 0);
      acc[1][0] = MFMA(a10, bfr[0][0], acc[1][0], 0, 0, 0);
      acc[1][1] = MFMA(a10, bfr[0][1], acc[1][1], 0, 0, 0);
      acc[0][0] = MFMA(a01, bfr[1][0], acc[0][0], 0, 0, 0);
      acc[0][1] = MFMA(a01, bfr[1][1], acc[0][1], 0, 0, 0);
      acc[1][0] = MFMA(a11, bfr[1][0], acc[1][0], 0, 0, 0);
      acc[1][1] = MFMA(a11, bfr[1][1], acc[1][1], 0, 0, 0);
      __builtin_amdgcn_s_setprio(0);
      __builtin_amdgcn_s_barrier();
    }
    // ---- phase 1: ks 2,3 ----
    {
      bf16x8 a02 = *(const bf16x8*)(asb + sBase0 + 2 * 2048 + aoff);
      bf16x8 a12 = *(const bf16x8*)(asb + sBase1 + 2 * 2048 + aoff);
      bf16x8 a03 = *(const bf16x8*)(asb + sBase0 + 3 * 2048 + aoff);
      bf16x8 a13 = *(const bf16x8*)(asb + sBase1 + 3 * 2048 + aoff);
      if (t < 126) issueA2(t + 2, (t + 2) & 3, 1);   // A(t+2) chunks 2,3
      // drain A(t+1) (4 oldest); keep B(t+1)x8 + A(t+2)x4 in flight
      if (t < 126)       asm volatile("s_waitcnt vmcnt(12)" ::: "memory");
      else if (t == 126) asm volatile("s_waitcnt vmcnt(8)" ::: "memory");
      else               asm volatile("s_waitcnt vmcnt(0)" ::: "memory");
      __builtin_amdgcn_s_barrier();
      __builtin_amdgcn_s_setprio(1);
      acc[0][0] = MFMA(a02, bfr[2][0], acc[0][0], 0, 0, 0);
      acc[0][1] = MFMA(a02, bfr[2][1], acc[0][1], 0, 0, 0);
      acc[1][0] = MFMA(a12, bfr[2][0], acc[1][0], 0, 0, 0);
      acc[1][1] = MFMA(a12, bfr[2][1], acc[1][1], 0, 0, 0);
      acc[0][0] = MFMA(a03, bfr[3][0], acc[0][0], 0, 0, 0);
      acc[0][1] = MFMA(a03, bfr[3][1], acc[0][1], 0, 0, 0);
      acc[1][0] = MFMA(a13, bfr[3][0], acc[1][0], 0, 0, 0);
      acc[1][1] = MFMA(a13, bfr[3][1], acc[1][1], 0, 0, 0);
      __builtin_amdgcn_s_setprio(0);
      if (t < 126) loadB(bfr, t + 2);                // refill this parity's reg set
      __builtin_amdgcn_s_barrier();
    }
  };

  #pragma unroll 1
  for (int it = 0; it < 32; ++it) {                  // x4-unrolled: static ring indices
    const int t = it * 4;
    step(t,     0, bA);
    step(t + 1, 1, bB);
    step(t + 2, 2, bA);
    step(t + 3, 3, bB);
  }

  // epilogue: C/D layout col=lane&31, row=(r&3)+8*(r>>2)+4*h (verified)
  const int c0 = nb * 128 + wn * 64 + ml;
  float bv0 = 0.f, bv1 = 0.f;
  #pragma unroll
  for (int p = 0; p < 32; ++p) {
    bv0 += bias_p[(size_t)p * 1024 + c0];
    bv1 += bias_p[(size_t)p * 1024 + c0 + 32];
  }
  const int r0 = mb2 * 256 + wm * 64;
  #pragma unroll
  for (int mt = 0; mt < 2; ++mt)
    #pragma unroll
    for (int r = 0; r < 16; ++r) {
      int row = r0 + mt * 32 + (r & 3) + 8 * (r >> 2) + 4 * h;
      float* po = out + (size_t)row * 1024 + c0;
      po[0]  = acc[mt][0][r] + bv0;
      po[32] = acc[mt][1][r] + bv1;
    }
}

// ============================ OLD FUSED PATH (fallback, verified 272us) ============================
__global__ __launch_bounds__(256)
void cheby_prep(const float* __restrict__ x, const float* __restrict__ C,
                bf16* __restrict__ Bt, float* __restrict__ bias_p,
                float* __restrict__ th) {
  const int bid = blockIdx.x, tid = threadIdx.x;
  if (bid >= 1024) {
    const int r = bid - 1024;
    f32x4 v = *(const f32x4*)(x + (size_t)r * 1024 + tid * 4);
    f32x4 t;
    #pragma unroll
    for (int j = 0; j < 4; ++j) t[j] = fast_tanh(v[j]);
    *(f32x2*)(th + (size_t)r * 1024 + tid * 2)       = (f32x2){t.x, t.z};
    *(f32x2*)(th + (size_t)r * 1024 + 512 + tid * 2) = (f32x2){t.y, t.w};
    return;
  }
  __shared__ float tile[32][292];
  const int i0 = (bid >> 5) * 32, o0 = (bid & 31) * 32;
  {
    const int r = tid >> 3, seg = tid & 7;
    const float* src = C + (size_t)(i0 + r) * 9216 + (size_t)o0 * 9 + seg * 36;
    float* dst = &tile[r][seg * 36];
    #pragma unroll
    for (int v = 0; v < 9; ++v) *(f32x4*)(dst + v * 4) = *(const f32x4*)(src + v * 4);
  }
  __syncthreads();
  #pragma unroll
  for (int j = 0; j < 4; ++j) {
    int e = tid + 256 * j;
    int il = e >> 5, ol = e & 31;
    int i = i0 + il, o = o0 + ol;
    bf16x8 v;
    #pragma unroll
    for (int d = 0; d < 8; ++d) v[d] = (bf16)tile[il][ol * 9 + 1 + d];
    size_t idx16 = ((size_t)((o >> 7) * 128 + (i >> 3)) * 8 + (i & 7)) * 128 + (o & 127);
    *(bf16x8*)&Bt[idx16 * 8] = v;
  }
  if (tid < 32) {
    float s = 0.f;
    #pragma unroll
    for (int i = 0; i < 32; ++i) s += tile[i][tid * 9];
    bias_p[(size_t)(bid >> 5) * 1024 + o0 + tid] = s;
  }
}

__global__ __launch_bounds__(256, 2)
void cheby_gemm(const float* __restrict__ th, const bf16* __restrict__ Bt,
                const float* __restrict__ bias_p, float* __restrict__ out) {
  __shared__ bf16 Bs[2][8192];
  const int tid  = threadIdx.x;
  const int lane = tid & 63, w = tid >> 6;
  const int wm = w >> 1, wn = w & 1;
  const int nb = blockIdx.x & 7, mb = blockIdx.x >> 3;
  const int t0 = mb * 128, o0 = nb * 128;
  const int ml = lane & 31, h = lane >> 5;

  const float* xr0 = th + (size_t)(t0 + wm * 64 + ml) * 1024 + h * 512;
  const float* xr1 = xr0 + 32 * 1024;
  const bf16* btw = Bt + ((size_t)nb * 128 * 1024 + (size_t)w * 256 + lane) * 8;

  f32x16 acc[2][2];
  #pragma unroll
  for (int a = 0; a < 2; ++a)
    #pragma unroll
    for (int b = 0; b < 2; ++b)
      #pragma unroll
      for (int r = 0; r < 16; ++r) acc[a][b][r] = 0.f;

  bf16x8 afrA[2][4], afrB[2][4];
  f32x4 xv0, xv1;

  auto gen = [&](bf16x8 (&dst)[2][4], f32x4 s0, f32x4 s1) {
    #pragma unroll
    for (int ks = 0; ks < 4; ++ks) {
      f32x2 t  = {s0[ks], s1[ks]};
      f32x2 t2 = t + t;
      f32x2 prev = {1.f, 1.f}, cur = t;
      #pragma unroll
      for (int j = 0; j < 8; ++j) {
        dst[0][ks][j] = (bf16)cur.x;
        dst[1][ks][j] = (bf16)cur.y;
        f32x2 nx = t2 * cur - prev;
        prev = cur; cur = nx;
      }
    }
  };

  {
    f32x4 s0 = *(const f32x4*)(xr0), s1 = *(const f32x4*)(xr1);
    gen(afrA, s0, s1);
    xv0 = *(const f32x4*)(xr0 + 4);
    xv1 = *(const f32x4*)(xr1 + 4);
  }
  #pragma unroll
  for (int b = 0; b < 4; ++b)
    g2lds16(btw + (size_t)b * 64 * 8, &Bs[0][(w * 256 + b * 64) * 8]);

  auto stage = [&](int s, int bi, bf16x8 (&cur)[2][4], bf16x8 (&nxt)[2][4]) {
    __syncthreads();
    if (s < 127) {
      const bf16* g = btw + (size_t)(s + 1) * 8192;
      #pragma unroll
      for (int b = 0; b < 4; ++b)
        g2lds16(g + (size_t)b * 64 * 8, &Bs[bi ^ 1][(w * 256 + b * 64) * 8]);
    }
    bf16x8 bfr[4][2];
    #pragma unroll
    for (int ks = 0; ks < 4; ++ks) {
      const int ce = ((ks * 2 + h) * 128 + wn * 64 + ml) * 8;
      bfr[ks][0] = *(const bf16x8*)&Bs[bi][ce];
      bfr[ks][1] = *(const bf16x8*)&Bs[bi][ce + 32 * 8];
    }
    if (s < 127) {
      gen(nxt, xv0, xv1);
      if (s < 126) {
        xv0 = *(const f32x4*)(xr0 + (s + 2) * 4);
        xv1 = *(const f32x4*)(xr1 + (s + 2) * 4);
      }
    }
    #pragma unroll
    for (int ks = 0; ks < 4; ++ks) {
      acc[0][0] = MFMA(cur[0][ks], bfr[ks][0], acc[0][0], 0, 0, 0);
      acc[0][1] = MFMA(cur[0][ks], bfr[ks][1], acc[0][1], 0, 0, 0);
      acc[1][0] = MFMA(cur[1][ks], bfr[ks][0], acc[1][0], 0, 0, 0);
      acc[1][1] = MFMA(cur[1][ks], bfr[ks][1], acc[1][1], 0, 0, 0);
    }
  };

  #pragma unroll 1
  for (int s2 = 0; s2 < 64; ++s2) {
    stage(2 * s2,     0, afrA, afrB);
    stage(2 * s2 + 1, 1, afrB, afrA);
  }

  const int c0 = o0 + wn * 64 + ml;
  float bv0 = 0.f, bv1 = 0.f;
  #pragma unroll
  for (int p = 0; p < 32; ++p) {
    bv0 += bias_p[(size_t)p * 1024 + c0];
    bv1 += bias_p[(size_t)p * 1024 + c0 + 32];
  }
  #pragma unroll
  for (int mt = 0; mt < 2; ++mt)
    #pragma unroll
    for (int r = 0; r < 16; ++r) {
      int row = t0 + wm * 64 + mt * 32 + (r & 3) + 8 * (r >> 2) + 4 * h;
      float* po = out + (size_t)row * 1024 + c0;
      po[0]  = acc[mt][0][r] + bv0;
      po[32] = acc[mt][1][r] + bv1;
    }
}

// ---- naive fallback (ws too small) — correct, slow, should never run
__global__ __launch_bounds__(256)
void cheby_naive(const float* __restrict__ x, const float* __restrict__ C,
                 float* __restrict__ out) {
  const int t = blockIdx.x, tid = threadIdx.x;
  float acc[4] = {0.f, 0.f, 0.f, 0.f};
  for (int i = 0; i < 1024; ++i) {
    float th = tanhf(x[(size_t)t * 1024 + i]);
    float T[9]; T[0] = 1.f; T[1] = th;
    #pragma unroll
    for (int d = 2; d < 9; ++d) T[d] = 2.f * th * T[d - 1] - T[d - 2];
    #pragma unroll
    for (int j = 0; j < 4; ++j) {
      const float* cp = &C[((size_t)i * 1024 + tid + j * 256) * 9];
      float s = 0.f;
      #pragma unroll
      for (int d = 0; d < 9; ++d) s += T[d] * cp[d];
      acc[j] += s;
    }
  }
  #pragma unroll
  for (int j = 0; j < 4; ++j) out[(size_t)t * 1024 + tid + j * 256] = acc[j];
}

extern "C" void kernel_launch(void* const* d_in, const int* in_sizes, int n_in,
                              void* d_out, int out_size, void* d_ws, size_t ws_size,
                              hipStream_t stream) {
  (void)in_sizes; (void)n_in; (void)out_size;
  const float* x = (const float*)d_in[0];
  const float* C = (const float*)d_in[1];
  float* out = (float*)d_out;

  const size_t a_bytes  = (size_t)8192 * 8192 * 2;        // 134.22 MB
  const size_t b_bytes  = (size_t)8 * 128 * 8192 * 2;     // 16.78 MB
  const size_t bp_bytes = (size_t)32 * 1024 * 4;          // 128 KB

  const size_t bt_bytes = (size_t)8 * 128 * 1024 * 8 * 2; // old fused path
  const size_t th_bytes = (size_t)8192 * 1024 * 4;

  if (ws_size >= a_bytes + b_bytes + bp_bytes) {
    bf16*  A      = (bf16*)d_ws;
    bf16*  B      = (bf16*)((char*)d_ws + a_bytes);
    float* bias_p = (float*)((char*)d_ws + a_bytes + b_bytes);
    cheby_prep2<<<2048, 256, 0, stream>>>(x, C, A, B, bias_p);
    cheby_gemm3<<<256, 512, 0, stream>>>(A, B, bias_p, out);
  } else if (ws_size >= bt_bytes + bp_bytes + th_bytes) {
    bf16*  Bt     = (bf16*)d_ws;
    float* bias_p = (float*)((char*)d_ws + bt_bytes);
    float* th     = (float*)((char*)d_ws + bt_bytes + bp_bytes);
    cheby_prep<<<9216, 256, 0, stream>>>(x, C, Bt, bias_p, th);
    cheby_gemm<<<512, 256, 0, stream>>>(th, Bt, bias_p, out);
  } else {
    cheby_naive<<<8192, 256, 0, stream>>>(x, C, out);
  }
}

// Round 3
// 254.425 us; speedup vs baseline: 1.1370x; 1.1370x over previous
//
#include <hip/hip_runtime.h>

// ChebyKANLayer: y[t,o] = bias[o] + sum_k A[t,k]*B[k,o], K=8192, k=i*8+(d-1), d=1..8.
// R9: gemm loop has ZERO global->VGPR loads: A and B both staged via global_load_lds
// into a 3-deep LDS ring (48 KB/buf), prefetch depth 2, ONE counted vmcnt(6) per
// K-step, raw barriers, setprio MFMA clusters, XCD swizzle. Fragment-packed A/B
// global images identical to the verified R7/R8 kernels.

typedef __bf16 bf16;
typedef __bf16 bf16x8 __attribute__((ext_vector_type(8)));
typedef float f32x2 __attribute__((ext_vector_type(2)));
typedef float f32x4 __attribute__((ext_vector_type(4)));
typedef float f32x16 __attribute__((ext_vector_type(16)));

#define MFMA __builtin_amdgcn_mfma_f32_32x32x16_bf16

__device__ __forceinline__ void g2lds16(const void* g, void* l) {
  __builtin_amdgcn_global_load_lds(
      (const __attribute__((address_space(1))) unsigned int*)g,
      (__attribute__((address_space(3))) unsigned int*)l, 16, 0, 0);
}

__device__ __forceinline__ float fast_tanh(float a) {
  float e = __expf(a + a);
  return 1.f - 2.f * __builtin_amdgcn_rcpf(e + 1.f);   // saturating, NaN-free
}

// ============================ PREP ============================
// A global layout: [mb 0..63][kt 0..127][tile image 8192 bf16], tile image elem:
//   (((ks*4 + m32)*2 + h)*32 + ml)*8 + j  with i = kt*8 + 2*ks + h, d = j+1,
//   row r within 128-slice: m32 = r>>5, ml = r&31.
// B global layout: [nb 0..7][kt 0..127][8192], same k mapping, n32=(o&127)>>5, o31=o&31.
// bias_p[p][o] = sum_{i in 32-block p} C[i][o][0].
__global__ __launch_bounds__(256)
void cheby_prep3(const float* __restrict__ x, const float* __restrict__ C,
                 bf16* __restrict__ A, bf16* __restrict__ B,
                 float* __restrict__ bias_p) {
  const int bid = blockIdx.x, tid = threadIdx.x;
  if (bid < 2048) {                                  // ---- A-gen: 64 rows x 64 i per block
    const int rb = bid >> 4, ig = bid & 15;
    const int rl = tid & 63, ih = tid >> 6;          // ih 0..3
    const int i_base = ig * 64 + ih * 16;
    const int mb = rb >> 1;
    const int rs = (rb & 1) * 64 + rl;               // row within 128-slice
    const int m32 = rs >> 5, ml = rs & 31;
    const float* xp = x + (size_t)(rb * 64 + rl) * 1024 + i_base;
    bf16* aout = A + (size_t)mb * 1048576;
    #pragma unroll
    for (int q = 0; q < 4; ++q) {
      f32x4 xv = *(const f32x4*)(xp + q * 4);
      #pragma unroll
      for (int j = 0; j < 4; ++j) {
        const int ia = i_base + q * 4 + j;
        const int kt = ia >> 3, cc = ia & 7;
        float z = fast_tanh(xv[j]);
        float z2 = z + z, pv = 1.f, cv = z;
        bf16x8 v;
        #pragma unroll
        for (int d = 0; d < 8; ++d) {
          v[d] = (bf16)cv;
          float nx = z2 * cv - pv; pv = cv; cv = nx;
        }
        const int widx = (((cc >> 1) * 4 + m32) * 2 + (cc & 1)) * 32 + ml;
        *(bf16x8*)(aout + (size_t)kt * 8192 + widx * 8) = v;
      }
    }
    return;
  }
  // ---- B repack + bias partials: 32 i x 32 o per block (1024 blocks)
  const int b2 = bid - 2048;
  __shared__ float tile[32][292];
  const int i0 = (b2 >> 5) * 32, o0 = (b2 & 31) * 32;
  {
    const int r = tid >> 3, seg = tid & 7;
    const float* src = C + (size_t)(i0 + r) * 9216 + (size_t)o0 * 9 + seg * 36;
    float* dst = &tile[r][seg * 36];
    #pragma unroll
    for (int v = 0; v < 9; ++v) *(f32x4*)(dst + v * 4) = *(const f32x4*)(src + v * 4);
  }
  __syncthreads();
  #pragma unroll
  for (int j = 0; j < 4; ++j) {
    int e = tid + 256 * j;
    int il = e >> 5, ol = e & 31;
    int i = i0 + il, o = o0 + ol;
    bf16x8 v;
    #pragma unroll
    for (int d = 0; d < 8; ++d) v[d] = (bf16)tile[il][ol * 9 + 1 + d];
    const int cc = i & 7;
    size_t tnum = (size_t)(o >> 7) * 128 + (i >> 3);
    const int widx = (((cc >> 1) * 4 + ((o & 127) >> 5)) * 2 + (cc & 1)) * 32 + (o & 31);
    *(bf16x8*)(B + tnum * 8192 + widx * 8) = v;
  }
  if (tid < 32) {
    float s = 0.f;
    #pragma unroll
    for (int i = 0; i < 32; ++i) s += tile[i][tid * 9];
    bias_p[(size_t)(b2 >> 5) * 1024 + o0 + tid] = s;
  }
}

// ============================ GEMM (all-LDS staging, counted vmcnt) ============================
// Block 256x128, 512 thr, 8 waves (4M x 2N), wave tile 64x64, BK=64, 128 K-steps.
// LDS ring[3]: per buf A[0..16384) (chunks c=0..3: c>>1 = 128-row slice, c&1 = img half),
// B[16384..24576) linear img. 6 g2lds/step. vmcnt(6) once per step.
__global__ __launch_bounds__(512, 1)
void cheby_gemm4(const bf16* __restrict__ A, const bf16* __restrict__ B,
                 const float* __restrict__ bias_p, float* __restrict__ out) {
  __shared__ bf16 ring[3][24576];                    // 3 x 48 KB = 144 KB
  const int tid = threadIdx.x;
  const int lane = tid & 63, w = tid >> 6;
  const int wm = w >> 1, wn = w & 1;
  const int bid = blockIdx.x;
  const int wgid = (bid & 7) * 32 + (bid >> 3);      // XCD-chunked, bijective (256 = 8*32)
  const int mb2 = wgid >> 3, nb = wgid & 7;

  const int ml = lane & 31, h = lane >> 5;
  const int aLane = h * 256 + ml * 8;                // lane part of fragment elem offset
  const int row0 = wm * 64, row1 = row0 + 32;        // the wave's two m-subtiles
  const int aBase0 = (row0 >> 7) * 8192 + ((row0 >> 5) & 3) * 512 + aLane;
  const int aBase1 = (row1 >> 7) * 8192 + ((row1 >> 5) & 3) * 512 + aLane;
  const int bBase  = 16384 + wn * 1024 + aLane;      // +nt*512, +ks*2048

  const bf16* aG = A + (size_t)(mb2 * 2) * 1048576 + tid * 8;   // slice0; slice1 at +1048576
  const bf16* bG = B + (size_t)nb * 1048576 + tid * 8;

  f32x16 acc[2][2];
  #pragma unroll
  for (int a = 0; a < 2; ++a)
    #pragma unroll
    for (int b = 0; b < 2; ++b)
      #pragma unroll
      for (int r = 0; r < 16; ++r) acc[a][b][r] = 0.f;

  // chunks 0,1 of A tile t (slice 0) -> ring[p]
  auto issueA01 = [&](int t, int p) {
    g2lds16(aG + (size_t)t * 8192,        &ring[p][tid * 8]);
    g2lds16(aG + (size_t)t * 8192 + 4096, &ring[p][4096 + tid * 8]);
  };
  // chunks 2,3 of A (slice 1) + both halves of B tile t -> ring[p]
  auto issueA23B = [&](int t, int p) {
    g2lds16(aG + 1048576 + (size_t)t * 8192,        &ring[p][8192 + tid * 8]);
    g2lds16(aG + 1048576 + (size_t)t * 8192 + 4096, &ring[p][12288 + tid * 8]);
    g2lds16(bG + (size_t)t * 8192,                  &ring[p][16384 + tid * 8]);
    g2lds16(bG + (size_t)t * 8192 + 4096,           &ring[p][20480 + tid * 8]);
  };

  // prologue: batch(0)->buf0, batch(1)->buf1; wait batch(0) (keep 6 in flight)
  issueA01(0, 0); issueA23B(0, 0);
  issueA01(1, 1); issueA23B(1, 1);
  asm volatile("s_waitcnt vmcnt(6)" ::: "memory");
  __builtin_amdgcn_s_barrier();

  auto step = [&](int t, int pc, int pn) {
    const bf16* ra = &ring[pc][0];
    const bool pf = (t + 2 < 128);
    // ---- phase 0: ks 0,1 ----
    {
      bf16x8 a00 = *(const bf16x8*)(ra + aBase0);
      bf16x8 a10 = *(const bf16x8*)(ra + aBase1);
      bf16x8 a01 = *(const bf16x8*)(ra + aBase0 + 2048);
      bf16x8 a11 = *(const bf16x8*)(ra + aBase1 + 2048);
      bf16x8 b00 = *(const bf16x8*)(ra + bBase);
      bf16x8 b10 = *(const bf16x8*)(ra + bBase + 512);
      bf16x8 b01 = *(const bf16x8*)(ra + bBase + 2048);
      bf16x8 b11 = *(const bf16x8*)(ra + bBase + 2048 + 512);
      if (pf) issueA01(t + 2, pn);
      __builtin_amdgcn_s_barrier();
      __builtin_amdgcn_s_setprio(1);
      acc[0][0] = MFMA(a00, b00, acc[0][0], 0, 0, 0);
      acc[0][1] = MFMA(a00, b10, acc[0][1], 0, 0, 0);
      acc[1][0] = MFMA(a10, b00, acc[1][0], 0, 0, 0);
      acc[1][1] = MFMA(a10, b10, acc[1][1], 0, 0, 0);
      acc[0][0] = MFMA(a01, b01, acc[0][0], 0, 0, 0);
      acc[0][1] = MFMA(a01, b11, acc[0][1], 0, 0, 0);
      acc[1][0] = MFMA(a11, b01, acc[1][0], 0, 0, 0);
      acc[1][1] = MFMA(a11, b11, acc[1][1], 0, 0, 0);
      __builtin_amdgcn_s_setprio(0);
      __builtin_amdgcn_s_barrier();
    }
    // ---- phase 1: ks 2,3 (A chunk half +4096; B img +4096) ----
    {
      bf16x8 a02 = *(const bf16x8*)(ra + aBase0 + 4096);
      bf16x8 a12 = *(const bf16x8*)(ra + aBase1 + 4096);
      bf16x8 a03 = *(const bf16x8*)(ra + aBase0 + 4096 + 2048);
      bf16x8 a13 = *(const bf16x8*)(ra + aBase1 + 4096 + 2048);
      bf16x8 b02 = *(const bf16x8*)(ra + bBase + 4096);
      bf16x8 b12 = *(const bf16x8*)(ra + bBase + 4096 + 512);
      bf16x8 b03 = *(const bf16x8*)(ra + bBase + 4096 + 2048);
      bf16x8 b13 = *(const bf16x8*)(ra + bBase + 4096 + 2048 + 512);
      if (pf) issueA23B(t + 2, pn);
      // batch(t+1) must be complete; batch(t+2) [6 ops] stays in flight
      if (t < 126) asm volatile("s_waitcnt vmcnt(6)" ::: "memory");
      else         asm volatile("s_waitcnt vmcnt(0)" ::: "memory");
      __builtin_amdgcn_s_barrier();
      __builtin_amdgcn_s_setprio(1);
      acc[0][0] = MFMA(a02, b02, acc[0][0], 0, 0, 0);
      acc[0][1] = MFMA(a02, b12, acc[0][1], 0, 0, 0);
      acc[1][0] = MFMA(a12, b02, acc[1][0], 0, 0, 0);
      acc[1][1] = MFMA(a12, b12, acc[1][1], 0, 0, 0);
      acc[0][0] = MFMA(a03, b03, acc[0][0], 0, 0, 0);
      acc[0][1] = MFMA(a03, b13, acc[0][1], 0, 0, 0);
      acc[1][0] = MFMA(a13, b03, acc[1][0], 0, 0, 0);
      acc[1][1] = MFMA(a13, b13, acc[1][1], 0, 0, 0);
      __builtin_amdgcn_s_setprio(0);
      __builtin_amdgcn_s_barrier();
    }
  };

  #pragma unroll 1
  for (int t3 = 0; t3 < 126; t3 += 3) {              // x3-unrolled: static ring indices
    step(t3,     0, 2);
    step(t3 + 1, 1, 0);
    step(t3 + 2, 2, 1);
  }
  step(126, 0, 2);                                   // pf=false
  step(127, 1, 0);                                   // pf=false

  // epilogue: C/D layout col=lane&31, row=(r&3)+8*(r>>2)+4*h (verified)
  const int c0 = nb * 128 + wn * 64 + ml;
  float bv0 = 0.f, bv1 = 0.f;
  #pragma unroll
  for (int p = 0; p < 32; ++p) {
    bv0 += bias_p[(size_t)p * 1024 + c0];
    bv1 += bias_p[(size_t)p * 1024 + c0 + 32];
  }
  const int r0 = mb2 * 256 + wm * 64;
  #pragma unroll
  for (int mt = 0; mt < 2; ++mt)
    #pragma unroll
    for (int r = 0; r < 16; ++r) {
      int row = r0 + mt * 32 + (r & 3) + 8 * (r >> 2) + 4 * h;
      float* po = out + (size_t)row * 1024 + c0;
      po[0]  = acc[mt][0][r] + bv0;
      po[32] = acc[mt][1][r] + bv1;
    }
}

// ---- naive fallback (ws too small) — correct, slow, should never run
__global__ __launch_bounds__(256)
void cheby_naive(const float* __restrict__ x, const float* __restrict__ C,
                 float* __restrict__ out) {
  const int t = blockIdx.x, tid = threadIdx.x;
  float acc[4] = {0.f, 0.f, 0.f, 0.f};
  for (int i = 0; i < 1024; ++i) {
    float th = tanhf(x[(size_t)t * 1024 + i]);
    float T[9]; T[0] = 1.f; T[1] = th;
    #pragma unroll
    for (int d = 2; d < 9; ++d) T[d] = 2.f * th * T[d - 1] - T[d - 2];
    #pragma unroll
    for (int j = 0; j < 4; ++j) {
      const float* cp = &C[((size_t)i * 1024 + tid + j * 256) * 9];
      float s = 0.f;
      #pragma unroll
      for (int d = 0; d < 9; ++d) s += T[d] * cp[d];
      acc[j] += s;
    }
  }
  #pragma unroll
  for (int j = 0; j < 4; ++j) out[(size_t)t * 1024 + tid + j * 256] = acc[j];
}

extern "C" void kernel_launch(void* const* d_in, const int* in_sizes, int n_in,
                              void* d_out, int out_size, void* d_ws, size_t ws_size,
                              hipStream_t stream) {
  (void)in_sizes; (void)n_in; (void)out_size;
  const float* x = (const float*)d_in[0];
  const float* C = (const float*)d_in[1];
  float* out = (float*)d_out;

  const size_t a_bytes  = (size_t)8192 * 8192 * 2;        // 134.22 MB
  const size_t b_bytes  = (size_t)8 * 128 * 8192 * 2;     // 16.78 MB
  const size_t bp_bytes = (size_t)32 * 1024 * 4;          // 128 KB

  if (ws_size >= a_bytes + b_bytes + bp_bytes) {
    bf16*  A      = (bf16*)d_ws;
    bf16*  B      = (bf16*)((char*)d_ws + a_bytes);
    float* bias_p = (float*)((char*)d_ws + a_bytes + b_bytes);
    cheby_prep3<<<3072, 256, 0, stream>>>(x, C, A, B, bias_p);
    cheby_gemm4<<<256, 512, 0, stream>>>(A, B, bias_p, out);
  } else {
    cheby_naive<<<8192, 256, 0, stream>>>(x, C, out);
  }
}

// Round 4
// 250.050 us; speedup vs baseline: 1.1569x; 1.0175x over previous
//
#include <hip/hip_runtime.h>

// ChebyKANLayer: y[t,o] = bias[o] + sum_k A[t,k]*B[k,o], K=8192, k=i*8+(d-1), d=1..8.
// R10: (a) gemm -> register-fragment software pipeline: frags(t) in VGPRs, MFMA(t)
// overlapped with ds_read of frags(t+1); ONE barrier + ONE counted vmcnt(6) per
// K-step (was 4 barriers). Ring[3] g2lds staging unchanged from verified R9.
// (b) prep A-gen stages x through LDS (coalesced reads, kills 4x x over-fetch).

typedef __bf16 bf16;
typedef __bf16 bf16x8 __attribute__((ext_vector_type(8)));
typedef float f32x2 __attribute__((ext_vector_type(2)));
typedef float f32x4 __attribute__((ext_vector_type(4)));
typedef float f32x16 __attribute__((ext_vector_type(16)));

#define MFMA __builtin_amdgcn_mfma_f32_32x32x16_bf16

__device__ __forceinline__ void g2lds16(const void* g, void* l) {
  __builtin_amdgcn_global_load_lds(
      (const __attribute__((address_space(1))) unsigned int*)g,
      (__attribute__((address_space(3))) unsigned int*)l, 16, 0, 0);
}

__device__ __forceinline__ float fast_tanh(float a) {
  float e = __expf(a + a);
  return 1.f - 2.f * __builtin_amdgcn_rcpf(e + 1.f);   // saturating, NaN-free
}

// ============================ PREP ============================
// A global layout: [mb 0..63][kt 0..127][tile image 8192 bf16], tile image elem:
//   (((ks*4 + m32)*2 + h)*32 + ml)*8 + j  with i = kt*8 + 2*ks + h, d = j+1,
//   row r within 128-slice: m32 = r>>5, ml = r&31.
// B global layout: [nb 0..7][kt 0..127][8192], same k mapping, n32=(o&127)>>5, o31=o&31.
// bias_p[p][o] = sum_{i in 32-block p} C[i][o][0].
__global__ __launch_bounds__(256)
void cheby_prep4(const float* __restrict__ x, const float* __restrict__ C,
                 bf16* __restrict__ A, bf16* __restrict__ B,
                 float* __restrict__ bias_p) {
  const int bid = blockIdx.x, tid = threadIdx.x;
  if (bid < 2048) {                                  // ---- A-gen: 64 rows x 64 i per block
    __shared__ float xs[64][65];                     // +1 pad: reads 2-way (free)
    const int rb = bid >> 4, ig = bid & 15;
    // coalesced stage: 64 rows x 64 i floats
    #pragma unroll
    for (int it = 0; it < 4; ++it) {
      const int e = tid + it * 256;                  // 0..1023 f32x4 groups
      const int rr = e >> 4, c4 = (e & 15) * 4;
      f32x4 v = *(const f32x4*)(x + (size_t)(rb * 64 + rr) * 1024 + ig * 64 + c4);
      xs[rr][c4 + 0] = v.x; xs[rr][c4 + 1] = v.y;
      xs[rr][c4 + 2] = v.z; xs[rr][c4 + 3] = v.w;
    }
    __syncthreads();
    const int rl = tid & 63, ih = tid >> 6;          // ih 0..3 -> 16-i sub-slice
    const int mb = rb >> 1;
    const int rs = (rb & 1) * 64 + rl;               // row within 128-slice
    const int m32 = rs >> 5, ml = rs & 31;
    bf16* aout = A + (size_t)mb * 1048576;
    #pragma unroll
    for (int q = 0; q < 4; ++q) {
      #pragma unroll
      for (int j = 0; j < 4; ++j) {
        const int il = ih * 16 + q * 4 + j;          // local i 0..63
        const int ia = ig * 64 + il;                 // global i
        const int kt = ia >> 3, cc = ia & 7;
        float z = fast_tanh(xs[rl][il]);
        float z2 = z + z, pv = 1.f, cv = z;
        bf16x8 v;
        #pragma unroll
        for (int d = 0; d < 8; ++d) {
          v[d] = (bf16)cv;
          float nx = z2 * cv - pv; pv = cv; cv = nx;
        }
        const int widx = (((cc >> 1) * 4 + m32) * 2 + (cc & 1)) * 32 + ml;
        *(bf16x8*)(aout + (size_t)kt * 8192 + widx * 8) = v;
      }
    }
    return;
  }
  // ---- B repack + bias partials: 32 i x 32 o per block (1024 blocks)
  const int b2 = bid - 2048;
  __shared__ float tile[32][292];
  const int i0 = (b2 >> 5) * 32, o0 = (b2 & 31) * 32;
  {
    const int r = tid >> 3, seg = tid & 7;
    const float* src = C + (size_t)(i0 + r) * 9216 + (size_t)o0 * 9 + seg * 36;
    float* dst = &tile[r][seg * 36];
    #pragma unroll
    for (int v = 0; v < 9; ++v) *(f32x4*)(dst + v * 4) = *(const f32x4*)(src + v * 4);
  }
  __syncthreads();
  #pragma unroll
  for (int j = 0; j < 4; ++j) {
    int e = tid + 256 * j;
    int il = e >> 5, ol = e & 31;
    int i = i0 + il, o = o0 + ol;
    bf16x8 v;
    #pragma unroll
    for (int d = 0; d < 8; ++d) v[d] = (bf16)tile[il][ol * 9 + 1 + d];
    const int cc = i & 7;
    size_t tnum = (size_t)(o >> 7) * 128 + (i >> 3);
    const int widx = (((cc >> 1) * 4 + ((o & 127) >> 5)) * 2 + (cc & 1)) * 32 + (o & 31);
    *(bf16x8*)(B + tnum * 8192 + widx * 8) = v;
  }
  if (tid < 32) {
    float s = 0.f;
    #pragma unroll
    for (int i = 0; i < 32; ++i) s += tile[i][tid * 9];
    bias_p[(size_t)(b2 >> 5) * 1024 + o0 + tid] = s;
  }
}

// ============================ GEMM (reg-frag software pipeline) ============================
// Block 256x128, 512 thr, 8 waves (4M x 2N), wave tile 64x64, BK=64, 128 K-steps.
// Ring[3] bufs of 48KB: A[0..16384) (c>>1 = 128-row slice, c&1 = img half), B[16384..24576).
// Tile t lives in buf t%3. Step t: issue batch(t+3) into buf t%3 (dead: read in step t-1,
// lgkmcnt(0)+barrier fenced); ds_read frags(t+1) from buf (t+1)%3 overlapped with
// MFMA on frags(t) held in regs; lgkmcnt(0); vmcnt(6); barrier. One barrier per step.
__global__ __launch_bounds__(512, 1)
void cheby_gemm5(const bf16* __restrict__ A, const bf16* __restrict__ B,
                 const float* __restrict__ bias_p, float* __restrict__ out) {
  __shared__ bf16 ring[3][24576];                    // 3 x 48 KB = 144 KB
  const int tid = threadIdx.x;
  const int lane = tid & 63, w = tid >> 6;
  const int wm = w >> 1, wn = w & 1;
  const int bid = blockIdx.x;
  const int wgid = (bid & 7) * 32 + (bid >> 3);      // XCD-chunked, bijective (256 = 8*32)
  const int mb2 = wgid >> 3, nb = wgid & 7;

  const int ml = lane & 31, h = lane >> 5;
  const int aLane = h * 256 + ml * 8;                // lane part of fragment elem offset
  const int row0 = wm * 64, row1 = row0 + 32;        // the wave's two m-subtiles
  const int aBase0 = (row0 >> 7) * 8192 + ((row0 >> 5) & 3) * 512 + aLane;
  const int aBase1 = (row1 >> 7) * 8192 + ((row1 >> 5) & 3) * 512 + aLane;
  const int bBase  = 16384 + wn * 1024 + aLane;      // +nt*512, +ks-offset

  const bf16* aG = A + (size_t)(mb2 * 2) * 1048576 + tid * 8;   // slice0; slice1 at +1048576
  const bf16* bG = B + (size_t)nb * 1048576 + tid * 8;

  f32x16 acc[2][2];
  #pragma unroll
  for (int a = 0; a < 2; ++a)
    #pragma unroll
    for (int b = 0; b < 2; ++b)
      #pragma unroll
      for (int r = 0; r < 16; ++r) acc[a][b][r] = 0.f;

  struct F { bf16x8 a0[4], a1[4], b0[4], b1[4]; };   // all-static indexing -> regs
  F f0, f1;

  auto issueB6 = [&](int t, int p) {                 // full batch: A 4 chunks + B 2 halves
    g2lds16(aG + (size_t)t * 8192,                  &ring[p][tid * 8]);
    g2lds16(aG + (size_t)t * 8192 + 4096,           &ring[p][4096 + tid * 8]);
    g2lds16(aG + 1048576 + (size_t)t * 8192,        &ring[p][8192 + tid * 8]);
    g2lds16(aG + 1048576 + (size_t)t * 8192 + 4096, &ring[p][12288 + tid * 8]);
    g2lds16(bG + (size_t)t * 8192,                  &ring[p][16384 + tid * 8]);
    g2lds16(bG + (size_t)t * 8192 + 4096,           &ring[p][20480 + tid * 8]);
  };
  auto loadFrags = [&](F& f, const bf16* ra) {
    #pragma unroll
    for (int ks = 0; ks < 4; ++ks) {
      const int off = (ks & 1) * 2048 + (ks >> 1) * 4096;
      f.a0[ks] = *(const bf16x8*)(ra + aBase0 + off);
      f.a1[ks] = *(const bf16x8*)(ra + aBase1 + off);
      f.b0[ks] = *(const bf16x8*)(ra + bBase + off);
      f.b1[ks] = *(const bf16x8*)(ra + bBase + off + 512);
    }
  };
  auto mfma16 = [&](F& c) {
    __builtin_amdgcn_s_setprio(1);
    #pragma unroll
    for (int ks = 0; ks < 4; ++ks) {
      acc[0][0] = MFMA(c.a0[ks], c.b0[ks], acc[0][0], 0, 0, 0);
      acc[0][1] = MFMA(c.a0[ks], c.b1[ks], acc[0][1], 0, 0, 0);
      acc[1][0] = MFMA(c.a1[ks], c.b0[ks], acc[1][0], 0, 0, 0);
      acc[1][1] = MFMA(c.a1[ks], c.b1[ks], acc[1][1], 0, 0, 0);
    }
    __builtin_amdgcn_s_setprio(0);
  };

  // prologue: batches 0,1,2 -> bufs 0,1,2; wait b0,b1 (keep b2's 6); frags(0) -> f0
  issueB6(0, 0); issueB6(1, 1); issueB6(2, 2);
  asm volatile("s_waitcnt vmcnt(6)" ::: "memory");
  __builtin_amdgcn_s_barrier();
  loadFrags(f0, &ring[0][0]);
  asm volatile("s_waitcnt lgkmcnt(0)" ::: "memory"); // all waves' tile-0 reads done
  __builtin_amdgcn_s_barrier();                      // -> buf0 overwritable at t=0

  auto step = [&](int t, int bufI, int bufR, F& cur, F& nxt, bool rd) {
    if (t + 3 < 128) issueB6(t + 3, bufI);           // bufI = t%3 (dead since end of t-1)
    if (rd) loadFrags(nxt, &ring[bufR][0]);          // bufR = (t+1)%3, overlaps MFMAs
    mfma16(cur);
    asm volatile("s_waitcnt lgkmcnt(0)" ::: "memory");  // frag reads done before barrier
    if (t < 125) asm volatile("s_waitcnt vmcnt(6)" ::: "memory");   // batch(t+2) landed
    else         asm volatile("s_waitcnt vmcnt(0)" ::: "memory");
    __builtin_amdgcn_s_barrier();
  };

  #pragma unroll 1
  for (int t6 = 0; t6 < 126; t6 += 6) {              // static bufs: t%3 = k%3, parity = k&1
    step(t6 + 0, 0, 1, f0, f1, true);
    step(t6 + 1, 1, 2, f1, f0, true);
    step(t6 + 2, 2, 0, f0, f1, true);
    step(t6 + 3, 0, 1, f1, f0, true);
    step(t6 + 4, 1, 2, f0, f1, true);
    step(t6 + 5, 2, 0, f1, f0, true);
  }
  step(126, 0, 1, f0, f1, true);
  step(127, 1, 2, f1, f0, false);

  // epilogue: C/D layout col=lane&31, row=(r&3)+8*(r>>2)+4*h (verified)
  const int c0 = nb * 128 + wn * 64 + ml;
  float bv0 = 0.f, bv1 = 0.f;
  #pragma unroll
  for (int p = 0; p < 32; ++p) {
    bv0 += bias_p[(size_t)p * 1024 + c0];
    bv1 += bias_p[(size_t)p * 1024 + c0 + 32];
  }
  const int r0 = mb2 * 256 + wm * 64;
  #pragma unroll
  for (int mt = 0; mt < 2; ++mt)
    #pragma unroll
    for (int r = 0; r < 16; ++r) {
      int row = r0 + mt * 32 + (r & 3) + 8 * (r >> 2) + 4 * h;
      float* po = out + (size_t)row * 1024 + c0;
      po[0]  = acc[mt][0][r] + bv0;
      po[32] = acc[mt][1][r] + bv1;
    }
}

// ---- naive fallback (ws too small) — correct, slow, should never run
__global__ __launch_bounds__(256)
void cheby_naive(const float* __restrict__ x, const float* __restrict__ C,
                 float* __restrict__ out) {
  const int t = blockIdx.x, tid = threadIdx.x;
  float acc[4] = {0.f, 0.f, 0.f, 0.f};
  for (int i = 0; i < 1024; ++i) {
    float th = tanhf(x[(size_t)t * 1024 + i]);
    float T[9]; T[0] = 1.f; T[1] = th;
    #pragma unroll
    for (int d = 2; d < 9; ++d) T[d] = 2.f * th * T[d - 1] - T[d - 2];
    #pragma unroll
    for (int j = 0; j < 4; ++j) {
      const float* cp = &C[((size_t)i * 1024 + tid + j * 256) * 9];
      float s = 0.f;
      #pragma unroll
      for (int d = 0; d < 9; ++d) s += T[d] * cp[d];
      acc[j] += s;
    }
  }
  #pragma unroll
  for (int j = 0; j < 4; ++j) out[(size_t)t * 1024 + tid + j * 256] = acc[j];
}

extern "C" void kernel_launch(void* const* d_in, const int* in_sizes, int n_in,
                              void* d_out, int out_size, void* d_ws, size_t ws_size,
                              hipStream_t stream) {
  (void)in_sizes; (void)n_in; (void)out_size;
  const float* x = (const float*)d_in[0];
  const float* C = (const float*)d_in[1];
  float* out = (float*)d_out;

  const size_t a_bytes  = (size_t)8192 * 8192 * 2;        // 134.22 MB
  const size_t b_bytes  = (size_t)8 * 128 * 8192 * 2;     // 16.78 MB
  const size_t bp_bytes = (size_t)32 * 1024 * 4;          // 128 KB

  if (ws_size >= a_bytes + b_bytes + bp_bytes) {
    bf16*  A      = (bf16*)d_ws;
    bf16*  B      = (bf16*)((char*)d_ws + a_bytes);
    float* bias_p = (float*)((char*)d_ws + a_bytes + b_bytes);
    cheby_prep4<<<3072, 256, 0, stream>>>(x, C, A, B, bias_p);
    cheby_gemm5<<<256, 512, 0, stream>>>(A, B, bias_p, out);
  } else {
    cheby_naive<<<8192, 256, 0, stream>>>(x, C, out);
  }
}